// Round 1
// baseline (1067.687 us; speedup 1.0000x reference)
//
#include <hip/hip_runtime.h>
#include <hip/hip_bf16.h>
#include <cstddef>

// Problem constants
#define NB 16
#define NC 1024      // coarse points per cloud
#define NF 4096      // fine points per cloud
#define CIN 256
#define CSKIP 128
#define HW_ 512      // hidden width
#define M_ROWS (NB * NF)          // 65536
#define H_ELEMS ((size_t)M_ROWS * HW_)   // 33554432
#define POS_ELEMS (M_ROWS * 3)           // 196608

// ---------------------------------------------------------------------------
// Kernel 1: brute-force kNN (K=3) + inverse-distance interpolation.
// One block = 256 queries of one cloud. Coarse positions staged in LDS.
// Phase 2: wave-cooperative feature gather (64 lanes x float4 = 256 channels).
// ---------------------------------------------------------------------------
__launch_bounds__(256)
__global__ void knn_interp_kernel(const float* __restrict__ x,
                                  const float* __restrict__ pos,
                                  const float* __restrict__ pos_skip,
                                  float* __restrict__ xi)
{
    __shared__ float sp[NC * 3];      // 12 KB coarse positions
    __shared__ int   s_idx[256 * 3];
    __shared__ float s_w[256 * 3];    // normalized weights

    const int tid   = threadIdx.x;
    const int cloud = blockIdx.x >> 4;       // 16 chunks per cloud
    const int chunk = blockIdx.x & 15;

    // stage coarse positions
    const float* pbase = pos + (size_t)cloud * NC * 3;
    for (int j = tid; j < NC * 3; j += 256) sp[j] = pbase[j];
    __syncthreads();

    const int q = chunk * 256 + tid;               // query idx within cloud
    const float* qp = pos_skip + ((size_t)cloud * NF + q) * 3;
    const float qx = qp[0], qy = qp[1], qz = qp[2];

    float b0 = 1e30f, b1 = 1e30f, b2 = 1e30f;
    int   i0 = 0, i1 = 0, i2 = 0;
    for (int j = 0; j < NC; ++j) {
        const float dx = qx - sp[3 * j + 0];
        const float dy = qy - sp[3 * j + 1];
        const float dz = qz - sp[3 * j + 2];
        const float d = dx * dx + dy * dy + dz * dz;
        if (d < b0)      { b2 = b1; i2 = i1; b1 = b0; i1 = i0; b0 = d; i0 = j; }
        else if (d < b1) { b2 = b1; i2 = i1; b1 = d;  i1 = j; }
        else if (d < b2) { b2 = d;  i2 = j; }
    }
    const float w0 = 1.0f / fmaxf(b0, 1e-16f);
    const float w1 = 1.0f / fmaxf(b1, 1e-16f);
    const float w2 = 1.0f / fmaxf(b2, 1e-16f);
    const float winv = 1.0f / (w0 + w1 + w2);
    s_idx[tid * 3 + 0] = i0; s_idx[tid * 3 + 1] = i1; s_idx[tid * 3 + 2] = i2;
    s_w[tid * 3 + 0] = w0 * winv; s_w[tid * 3 + 1] = w1 * winv; s_w[tid * 3 + 2] = w2 * winv;
    __syncthreads();

    // Phase 2: gather. 4 waves; each wave handles one query at a time,
    // 64 lanes x float4 covers all 256 channels of a row.
    const int wave = tid >> 6, lane = tid & 63;
    const float* xc = x + (size_t)cloud * NC * CIN;
    float* xo = xi + ((size_t)cloud * NF + chunk * 256) * CIN;
    for (int qq = wave; qq < 256; qq += 4) {
        const int   j0 = s_idx[qq * 3 + 0], j1 = s_idx[qq * 3 + 1], j2 = s_idx[qq * 3 + 2];
        const float u0 = s_w[qq * 3 + 0],   u1 = s_w[qq * 3 + 1],   u2 = s_w[qq * 3 + 2];
        const float4 f0 = ((const float4*)(xc + (size_t)j0 * CIN))[lane];
        const float4 f1 = ((const float4*)(xc + (size_t)j1 * CIN))[lane];
        const float4 f2 = ((const float4*)(xc + (size_t)j2 * CIN))[lane];
        float4 o;
        o.x = u0 * f0.x + u1 * f1.x + u2 * f2.x;
        o.y = u0 * f0.y + u1 * f1.y + u2 * f2.y;
        o.z = u0 * f0.z + u1 * f1.z + u2 * f2.z;
        o.w = u0 * f0.w + u1 * f1.w + u2 * f2.w;
        ((float4*)(xo + (size_t)qq * CIN))[lane] = o;
    }
}

// ---------------------------------------------------------------------------
// Kernel 2: fp32 GEMM (M x K) @ (K x 512) fused with bias -> ReLU -> BN affine.
// A may be split column-wise over two sources (concat fusion).
// 128x128 tile, BK=16, 256 threads, 8x8 micro-tile, register prefetch.
// ---------------------------------------------------------------------------
#define BM 128
#define BN 128
#define BKK 16
#define LDT 132   // padded LDS stride (floats); 132%4==0 keeps float4 alignment

__launch_bounds__(256, 2)
__global__ void gemm_relu_bn(const float* __restrict__ A0, int lda0,
                             const float* __restrict__ A1, int lda1, int ksplit,
                             const float* __restrict__ Bw, int K,
                             const float* __restrict__ bias,
                             const float* __restrict__ gamma,
                             const float* __restrict__ beta,
                             const float* __restrict__ mean,
                             const float* __restrict__ var,
                             float* __restrict__ C)
{
    __shared__ float As[BKK * LDT];
    __shared__ float Bs[BKK * LDT];

    const int tid = threadIdx.x;
    const int tx = tid & 15;          // n
    const int ty = tid >> 4;          // m
    const int bm = blockIdx.y * BM;
    const int bn = blockIdx.x * BN;

    // A loader geometry: 2 rows/thread, each a float4 of K
    const int arow0 = tid >> 2;             // 0..63
    const int akk   = (tid & 3) * 4;        // 0,4,8,12
    // B loader geometry: 2 float4/thread
    const int bk  = tid >> 5;               // 0..7
    const int bn4 = (tid & 31) * 4;         // 0..124

    float acc[8][8];
#pragma unroll
    for (int i = 0; i < 8; ++i)
#pragma unroll
        for (int j = 0; j < 8; ++j) acc[i][j] = 0.0f;

    float4 pa[2], pb[2];

    auto loadA = [&](int k0, int i) -> float4 {
        const int row = bm + arow0 + i * 64;
        const int kg  = k0 + akk;
        const float* src = (kg < ksplit)
            ? (A0 + (size_t)row * lda0 + kg)
            : (A1 + (size_t)row * lda1 + (kg - ksplit));
        return *(const float4*)src;
    };
    auto loadB = [&](int k0, int i) -> float4 {
        return *(const float4*)(Bw + (size_t)(k0 + bk + i * 8) * HW_ + bn + bn4);
    };

    pa[0] = loadA(0, 0); pa[1] = loadA(0, 1);
    pb[0] = loadB(0, 0); pb[1] = loadB(0, 1);

    const int nk = K / BKK;
    for (int t = 0; t < nk; ++t) {
#pragma unroll
        for (int i = 0; i < 2; ++i) {
            const int row = arow0 + i * 64;
            As[(akk + 0) * LDT + row] = pa[i].x;
            As[(akk + 1) * LDT + row] = pa[i].y;
            As[(akk + 2) * LDT + row] = pa[i].z;
            As[(akk + 3) * LDT + row] = pa[i].w;
            *(float4*)&Bs[(bk + i * 8) * LDT + bn4] = pb[i];
        }
        __syncthreads();
        if (t + 1 < nk) {
            pa[0] = loadA((t + 1) * BKK, 0); pa[1] = loadA((t + 1) * BKK, 1);
            pb[0] = loadB((t + 1) * BKK, 0); pb[1] = loadB((t + 1) * BKK, 1);
        }
#pragma unroll
        for (int k = 0; k < BKK; ++k) {
            const float4 a0 = *(const float4*)&As[k * LDT + ty * 8];
            const float4 a1 = *(const float4*)&As[k * LDT + ty * 8 + 4];
            const float4 b0 = *(const float4*)&Bs[k * LDT + tx * 8];
            const float4 b1 = *(const float4*)&Bs[k * LDT + tx * 8 + 4];
            const float av[8] = {a0.x, a0.y, a0.z, a0.w, a1.x, a1.y, a1.z, a1.w};
            const float bv[8] = {b0.x, b0.y, b0.z, b0.w, b1.x, b1.y, b1.z, b1.w};
#pragma unroll
            for (int i = 0; i < 8; ++i)
#pragma unroll
                for (int j = 0; j < 8; ++j)
                    acc[i][j] = fmaf(av[i], bv[j], acc[i][j]);
        }
        __syncthreads();
    }

    // epilogue: relu(acc + bias) * s + (beta - mean * s)
    const int gn = bn + tx * 8;
    float sc[8], sh[8], bb[8];
#pragma unroll
    for (int j = 0; j < 8; ++j) {
        const int c = gn + j;
        const float s = gamma[c] / sqrtf(var[c] + 1e-5f);
        sc[j] = s; sh[j] = beta[c] - mean[c] * s; bb[j] = bias[c];
    }
    const int gm = bm + ty * 8;
#pragma unroll
    for (int i = 0; i < 8; ++i) {
        float o[8];
#pragma unroll
        for (int j = 0; j < 8; ++j) {
            float v = acc[i][j] + bb[j];
            v = fmaxf(v, 0.0f);
            o[j] = v * sc[j] + sh[j];
        }
        float* crow = C + (size_t)(gm + i) * HW_ + gn;
        *(float4*)(crow)     = make_float4(o[0], o[1], o[2], o[3]);
        *(float4*)(crow + 4) = make_float4(o[4], o[5], o[6], o[7]);
    }
}

// ---------------------------------------------------------------------------
// Kernel 3: tail outputs — pos_skip copy + batch_skip (layout per out_size).
// mode 0: batch as float (tail==65536 elems); mode 1: batch as int64 words.
// ---------------------------------------------------------------------------
__launch_bounds__(256)
__global__ void tail_kernel(const float* __restrict__ pos_skip,
                            float* __restrict__ outp, int mode)
{
    const int i = blockIdx.x * 256 + threadIdx.x;
    if (i < POS_ELEMS) outp[i] = pos_skip[i];
    const int bi = i - POS_ELEMS;
    if (bi >= 0 && bi < M_ROWS) {
        if (mode == 0) {
            outp[POS_ELEMS + bi] = (float)(bi >> 12);
        } else {
            ((unsigned long long*)(outp + POS_ELEMS))[bi] = (unsigned long long)(bi >> 12);
        }
    }
}

// ---------------------------------------------------------------------------
extern "C" void kernel_launch(void* const* d_in, const int* in_sizes, int n_in,
                              void* d_out, int out_size, void* d_ws, size_t ws_size,
                              hipStream_t stream)
{
    const float* x        = (const float*)d_in[0];
    const float* pos      = (const float*)d_in[1];
    const float* x_skip   = (const float*)d_in[3];
    const float* pos_skip = (const float*)d_in[4];
    const float* w1  = (const float*)d_in[6];
    const float* b1  = (const float*)d_in[7];
    const float* g1  = (const float*)d_in[8];
    const float* be1 = (const float*)d_in[9];
    const float* m1  = (const float*)d_in[10];
    const float* v1  = (const float*)d_in[11];
    const float* w2  = (const float*)d_in[12];
    const float* b2  = (const float*)d_in[13];
    const float* g2  = (const float*)d_in[14];
    const float* be2 = (const float*)d_in[15];
    const float* m2  = (const float*)d_in[16];
    const float* v2  = (const float*)d_in[17];

    float* out = (float*)d_out;
    float* xi  = out;            // scratch: first 64 MB of d_out (overwritten by GEMM2 later)
    float* h1  = (float*)d_ws;   // 128 MB hidden activations

    // 1) kNN interpolation -> xi [65536, 256]
    knn_interp_kernel<<<256, 256, 0, stream>>>(x, pos, pos_skip, xi);

    // 2) Layer 1: [xi | x_skip] (65536x384) @ w1 (384x512) + epilogue -> h1
    gemm_relu_bn<<<dim3(BN / 128 * 4, M_ROWS / BM), 256, 0, stream>>>(
        xi, CIN, x_skip, CSKIP, CIN, w1, CIN + CSKIP,
        b1, g1, be1, m1, v1, h1);

    // 3) Layer 2: h1 (65536x512) @ w2 (512x512) + epilogue -> out[0 : 33.5M)
    gemm_relu_bn<<<dim3(4, M_ROWS / BM), 256, 0, stream>>>(
        h1, HW_, nullptr, 0, HW_, w2, HW_,
        b2, g2, be2, m2, v2, out);

    // 4) tail outputs
    const long long tail = (long long)out_size - (long long)H_ELEMS;
    if (tail > 0) {
        const int mode = (tail - POS_ELEMS >= 2 * M_ROWS) ? 1 : 0;
        tail_kernel<<<(POS_ELEMS + M_ROWS + 255) / 256, 256, 0, stream>>>(
            pos_skip, out + H_ELEMS, mode);
    }
}

// Round 2
// 737.123 us; speedup vs baseline: 1.4485x; 1.4485x over previous
//
#include <hip/hip_runtime.h>
#include <hip/hip_bf16.h>
#include <cstddef>
#include <cstdint>

// Problem constants
#define NB 16
#define NC 1024
#define NF 4096
#define CIN 256
#define CSKIP 128
#define HW_ 512
#define K1 (CIN + CSKIP)                  // 384
#define M_ROWS (NB * NF)                  // 65536
#define H_ELEMS ((size_t)M_ROWS * HW_)    // 33554432
#define POS_ELEMS (M_ROWS * 3)            // 196608

typedef __attribute__((ext_vector_type(8))) short bf16x8;
typedef __attribute__((ext_vector_type(4))) float f32x4;

__device__ __forceinline__ unsigned short f2bf(float f) {
    union { __hip_bfloat16 h; unsigned short u; } cv;
    cv.h = __float2bfloat16(f);
    return cv.u;
}
__device__ __forceinline__ float bf2f(unsigned short u) {
    union { __hip_bfloat16 h; unsigned short u; } cv;
    cv.u = u;
    return __bfloat162float(cv.h);
}
// split v into hi (bf16) and lo (bf16 of remainder)
__device__ __forceinline__ void split2(float v, unsigned short& hi, unsigned short& lo) {
    hi = f2bf(v);
    lo = f2bf(v - bf2f(hi));
}

#define GLOAD_LDS(gsrc, ldst)                                                            \
    __builtin_amdgcn_global_load_lds((const __attribute__((address_space(1))) void*)(gsrc), \
                                     (__attribute__((address_space(3))) void*)(ldst), 16, 0, 0)

// ---------------------------------------------------------------------------
// Kernel 1: kNN (K=3) + inverse-distance interpolation -> split bf16 planes
// (columns 0..255 of the concat A1 matrix, row stride K1=384).
// ---------------------------------------------------------------------------
__launch_bounds__(256)
__global__ void knn_interp_kernel(const float* __restrict__ x,
                                  const float* __restrict__ pos,
                                  const float* __restrict__ pos_skip,
                                  unsigned short* __restrict__ Ahi,
                                  unsigned short* __restrict__ Alo)
{
    __shared__ float sp[NC * 3];
    __shared__ int   s_idx[256 * 3];
    __shared__ float s_w[256 * 3];

    const int tid   = threadIdx.x;
    const int cloud = blockIdx.x >> 4;
    const int chunk = blockIdx.x & 15;

    const float* pbase = pos + (size_t)cloud * NC * 3;
    for (int j = tid; j < NC * 3; j += 256) sp[j] = pbase[j];
    __syncthreads();

    const int q = chunk * 256 + tid;
    const float* qp = pos_skip + ((size_t)cloud * NF + q) * 3;
    const float qx = qp[0], qy = qp[1], qz = qp[2];

    float b0 = 1e30f, b1 = 1e30f, b2 = 1e30f;
    int   i0 = 0, i1 = 0, i2 = 0;
    for (int j = 0; j < NC; ++j) {
        const float dx = qx - sp[3 * j + 0];
        const float dy = qy - sp[3 * j + 1];
        const float dz = qz - sp[3 * j + 2];
        const float d = dx * dx + dy * dy + dz * dz;
        if (d < b0)      { b2 = b1; i2 = i1; b1 = b0; i1 = i0; b0 = d; i0 = j; }
        else if (d < b1) { b2 = b1; i2 = i1; b1 = d;  i1 = j; }
        else if (d < b2) { b2 = d;  i2 = j; }
    }
    const float w0 = 1.0f / fmaxf(b0, 1e-16f);
    const float w1 = 1.0f / fmaxf(b1, 1e-16f);
    const float w2 = 1.0f / fmaxf(b2, 1e-16f);
    const float winv = 1.0f / (w0 + w1 + w2);
    s_idx[tid * 3 + 0] = i0; s_idx[tid * 3 + 1] = i1; s_idx[tid * 3 + 2] = i2;
    s_w[tid * 3 + 0] = w0 * winv; s_w[tid * 3 + 1] = w1 * winv; s_w[tid * 3 + 2] = w2 * winv;
    __syncthreads();

    const int wave = tid >> 6, lane = tid & 63;
    const float* xc = x + (size_t)cloud * NC * CIN;
    const size_t rowbase = (size_t)cloud * NF + chunk * 256;
    for (int qq = wave; qq < 256; qq += 4) {
        const int   j0 = s_idx[qq * 3 + 0], j1 = s_idx[qq * 3 + 1], j2 = s_idx[qq * 3 + 2];
        const float u0 = s_w[qq * 3 + 0],   u1 = s_w[qq * 3 + 1],   u2 = s_w[qq * 3 + 2];
        const float4 f0 = ((const float4*)(xc + (size_t)j0 * CIN))[lane];
        const float4 f1 = ((const float4*)(xc + (size_t)j1 * CIN))[lane];
        const float4 f2 = ((const float4*)(xc + (size_t)j2 * CIN))[lane];
        float o[4];
        o[0] = u0 * f0.x + u1 * f1.x + u2 * f2.x;
        o[1] = u0 * f0.y + u1 * f1.y + u2 * f2.y;
        o[2] = u0 * f0.z + u1 * f1.z + u2 * f2.z;
        o[3] = u0 * f0.w + u1 * f1.w + u2 * f2.w;
        unsigned short h[4], l[4];
#pragma unroll
        for (int c = 0; c < 4; ++c) split2(o[c], h[c], l[c]);
        uint2 hv, lv;
        hv.x = (unsigned)h[0] | ((unsigned)h[1] << 16);
        hv.y = (unsigned)h[2] | ((unsigned)h[3] << 16);
        lv.x = (unsigned)l[0] | ((unsigned)l[1] << 16);
        lv.y = (unsigned)l[2] | ((unsigned)l[3] << 16);
        const size_t ro = (rowbase + qq) * K1;
        ((uint2*)(Ahi + ro))[lane] = hv;
        ((uint2*)(Alo + ro))[lane] = lv;
    }
}

// ---------------------------------------------------------------------------
// Kernel 2: x_skip [M][128] f32 -> split planes at columns 256..383 of A1.
// ---------------------------------------------------------------------------
__launch_bounds__(256)
__global__ void conv_skip_kernel(const float* __restrict__ xs,
                                 unsigned short* __restrict__ Ahi,
                                 unsigned short* __restrict__ Alo)
{
    const int idx = blockIdx.x * 256 + threadIdx.x;   // M_ROWS * 32 threads
    const int row = idx >> 5;
    const int c4  = idx & 31;
    const float4 v = ((const float4*)(xs + (size_t)row * CSKIP))[c4];
    const float o[4] = {v.x, v.y, v.z, v.w};
    unsigned short h[4], l[4];
#pragma unroll
    for (int c = 0; c < 4; ++c) split2(o[c], h[c], l[c]);
    uint2 hv, lv;
    hv.x = (unsigned)h[0] | ((unsigned)h[1] << 16);
    hv.y = (unsigned)h[2] | ((unsigned)h[3] << 16);
    lv.x = (unsigned)l[0] | ((unsigned)l[1] << 16);
    lv.y = (unsigned)l[2] | ((unsigned)l[3] << 16);
    const size_t off = (size_t)row * K1 + CIN + c4 * 4;
    *(uint2*)(Ahi + off) = hv;
    *(uint2*)(Alo + off) = lv;
}

// ---------------------------------------------------------------------------
// Kernel 3: weight transpose + split: w [Kd][512] f32 -> WT planes [512][Kd] bf16.
// ---------------------------------------------------------------------------
__launch_bounds__(256)
__global__ void conv_w_kernel(const float* __restrict__ w,
                              unsigned short* __restrict__ WhiT,
                              unsigned short* __restrict__ WloT, int Kd)
{
    const int idx = blockIdx.x * 256 + threadIdx.x;
    if (idx >= Kd * 512) return;
    const int k = idx >> 9;
    const int n = idx & 511;
    const float v = w[(size_t)k * 512 + n];
    unsigned short h, l;
    split2(v, h, l);
    WhiT[(size_t)n * Kd + k] = h;
    WloT[(size_t)n * Kd + k] = l;
}

// ---------------------------------------------------------------------------
// Kernel 4: bf16 split NT-GEMM with MFMA 16x16x32, fused bias->ReLU->BN.
// C[M][512] = A[M][K] @ W^T where A = Ahi+Alo, W = Whi+Wlo (keep hh+hl+lh).
// K' = 3K regions: (Ahi,Whi), (Ahi,Wlo), (Alo,Whi).
// 128x128 tile, BK=32, 4 waves (2x2), 4x4 16x16 frags/wave, double-buffered
// LDS staged via global_load_lds (linear dest, XOR-swizzled per-lane source).
// ---------------------------------------------------------------------------
template <bool SPLIT_OUT>
__launch_bounds__(256)
__global__ void gemm_bf3s(const unsigned short* __restrict__ Ahi,
                          const unsigned short* __restrict__ Alo,
                          const unsigned short* __restrict__ Whi,   // [512][K]
                          const unsigned short* __restrict__ Wlo,
                          int K,
                          const float* __restrict__ bias,
                          const float* __restrict__ gamma,
                          const float* __restrict__ beta,
                          const float* __restrict__ mean,
                          const float* __restrict__ var,
                          float* __restrict__ Cf,
                          unsigned short* __restrict__ Chi,
                          unsigned short* __restrict__ Clo)
{
    __shared__ alignas(16) unsigned short As[2][128 * 32];
    __shared__ alignas(16) unsigned short Bs[2][128 * 32];

    const int tid  = threadIdx.x;
    const int lane = tid & 63;
    const int wv   = tid >> 6;      // 0..3
    const int wr   = wv >> 1;       // output row half
    const int wc   = wv & 1;        // output col half
    const int bm   = blockIdx.y * 128;
    const int bn   = blockIdx.x * 128;

    const int sr  = lane >> 2;      // staging: row within 16-row chunk
    const int sgp = lane & 3;       // staging: physical 16B granule

    f32x4 acc[4][4];
#pragma unroll
    for (int i = 0; i < 4; ++i)
#pragma unroll
        for (int j = 0; j < 4; ++j) acc[i][j] = (f32x4){0.f, 0.f, 0.f, 0.f};

    const int NT = 3 * K / 32;

    auto stage = [&](int buf, int t) {
        const int kp = t * 32;
        const int region = kp / K;
        const int kk = kp - region * K;
        const unsigned short* Ap = (region < 2) ? Ahi : Alo;
        const unsigned short* Bp = (region == 1) ? Wlo : Whi;
#pragma unroll
        for (int i = 0; i < 2; ++i) {
            const int r = wv * 32 + i * 16 + sr;                 // tile-local row
            const int g = sgp ^ ((r >> 1) & 3);                  // logical granule
            GLOAD_LDS(Ap + (size_t)(bm + r) * K + kk + g * 8,
                      &As[buf][(wv * 32 + i * 16) * 32]);
        }
#pragma unroll
        for (int i = 0; i < 2; ++i) {
            const int r = wv * 32 + i * 16 + sr;                 // tile-local col of C
            const int g = sgp ^ ((r >> 1) & 3);
            GLOAD_LDS(Bp + (size_t)(bn + r) * K + kk + g * 8,
                      &Bs[buf][(wv * 32 + i * 16) * 32]);
        }
    };

    int cur = 0;
    stage(0, 0);
    for (int t = 0; t < NT; ++t) {
        __syncthreads();                       // drains vmcnt -> tile t visible
        if (t + 1 < NT) stage(cur ^ 1, t + 1); // prefetch next tile (in flight under compute)

        bf16x8 af[4], bw[4];
#pragma unroll
        for (int i = 0; i < 4; ++i) {
            const int r  = wr * 64 + i * 16 + (lane & 15);
            const int ga = (lane >> 4) ^ ((r >> 1) & 3);
            af[i] = *(const bf16x8*)&As[cur][r * 32 + ga * 8];
            const int c  = wc * 64 + i * 16 + (lane & 15);
            const int gb = (lane >> 4) ^ ((c >> 1) & 3);
            bw[i] = *(const bf16x8*)&Bs[cur][c * 32 + gb * 8];
        }
#pragma unroll
        for (int i = 0; i < 4; ++i)
#pragma unroll
            for (int j = 0; j < 4; ++j)
                acc[i][j] = __builtin_amdgcn_mfma_f32_16x16x32_bf16(af[i], bw[j], acc[i][j], 0, 0, 0);
        cur ^= 1;
    }

    // epilogue: relu(acc + bias) * s + (beta - mean*s); C row=(lane>>4)*4+q, col=lane&15
    const int lc  = lane & 15;
    const int lr4 = (lane >> 4) * 4;
#pragma unroll
    for (int j = 0; j < 4; ++j) {
        const int col = bn + wc * 64 + j * 16 + lc;
        const float s  = gamma[col] / sqrtf(var[col] + 1e-5f);
        const float sh = beta[col] - mean[col] * s;
        const float bb = bias[col];
#pragma unroll
        for (int i = 0; i < 4; ++i) {
            const f32x4 v = acc[i][j];
#pragma unroll
            for (int q = 0; q < 4; ++q) {
                const int row = bm + wr * 64 + i * 16 + lr4 + q;
                const float val = fmaxf(v[q] + bb, 0.f) * s + sh;
                const size_t off = (size_t)row * HW_ + col;
                if (SPLIT_OUT) {
                    unsigned short h, l;
                    split2(val, h, l);
                    Chi[off] = h;
                    Clo[off] = l;
                } else {
                    Cf[off] = val;
                }
            }
        }
    }
}

// ---------------------------------------------------------------------------
// Kernel 5: tail outputs (pos_skip copy + batch ids). Runs LAST — also
// overwrites the W2^T scratch that was parked in the tail region.
// ---------------------------------------------------------------------------
__launch_bounds__(256)
__global__ void tail_kernel(const float* __restrict__ pos_skip,
                            float* __restrict__ outp, int mode)
{
    const int i = blockIdx.x * 256 + threadIdx.x;
    if (i < POS_ELEMS) outp[i] = pos_skip[i];
    const int bi = i - POS_ELEMS;
    if (bi >= 0 && bi < M_ROWS) {
        if (mode == 0) {
            outp[POS_ELEMS + bi] = (float)(bi >> 12);
        } else {
            ((unsigned long long*)(outp + POS_ELEMS))[bi] = (unsigned long long)(bi >> 12);
        }
    }
}

// ---------------------------------------------------------------------------
extern "C" void kernel_launch(void* const* d_in, const int* in_sizes, int n_in,
                              void* d_out, int out_size, void* d_ws, size_t ws_size,
                              hipStream_t stream)
{
    const float* x        = (const float*)d_in[0];
    const float* pos      = (const float*)d_in[1];
    const float* x_skip   = (const float*)d_in[3];
    const float* pos_skip = (const float*)d_in[4];
    const float* w1  = (const float*)d_in[6];
    const float* b1  = (const float*)d_in[7];
    const float* g1  = (const float*)d_in[8];
    const float* be1 = (const float*)d_in[9];
    const float* m1  = (const float*)d_in[10];
    const float* v1  = (const float*)d_in[11];
    const float* w2  = (const float*)d_in[12];
    const float* b2  = (const float*)d_in[13];
    const float* g2  = (const float*)d_in[14];
    const float* be2 = (const float*)d_in[15];
    const float* m2  = (const float*)d_in[16];
    const float* v2  = (const float*)d_in[17];

    float* out = (float*)d_out;

    // scratch layout:
    //   d_out[0 .. 96.75MB): A1 planes + W1^T planes (dead before GEMM2 writes d_out)
    //   d_out tail [H_ELEMS*4 .. +1MB): W2^T planes (GEMM2 reads; tail_kernel overwrites after)
    //   d_ws[0 .. 128MB): h1 planes (GEMM2 input)
    unsigned short* A1hi = (unsigned short*)d_out;
    unsigned short* A1lo = A1hi + (size_t)M_ROWS * K1;
    unsigned short* W1hi = A1lo + (size_t)M_ROWS * K1;
    unsigned short* W1lo = W1hi + (size_t)512 * K1;
    unsigned short* W2hi = (unsigned short*)(out + H_ELEMS);
    unsigned short* W2lo = W2hi + (size_t)512 * 512;
    unsigned short* h1hi = (unsigned short*)d_ws;
    unsigned short* h1lo = h1hi + H_ELEMS;

    // 1) producers
    knn_interp_kernel<<<256, 256, 0, stream>>>(x, pos, pos_skip, A1hi, A1lo);
    conv_skip_kernel<<<M_ROWS * 32 / 256, 256, 0, stream>>>(x_skip, A1hi, A1lo);
    conv_w_kernel<<<(K1 * 512 + 255) / 256, 256, 0, stream>>>(w1, W1hi, W1lo, K1);
    conv_w_kernel<<<(512 * 512 + 255) / 256, 256, 0, stream>>>(w2, W2hi, W2lo, 512);

    // 2) Layer 1: [65536 x 384] @ [384 x 512] -> split h1 planes
    gemm_bf3s<true><<<dim3(4, M_ROWS / 128), 256, 0, stream>>>(
        A1hi, A1lo, W1hi, W1lo, K1, b1, g1, be1, m1, v1,
        nullptr, h1hi, h1lo);

    // 3) Layer 2: [65536 x 512] @ [512 x 512] -> f32 out
    gemm_bf3s<false><<<dim3(4, M_ROWS / 128), 256, 0, stream>>>(
        h1hi, h1lo, W2hi, W2lo, HW_, b2, g2, be2, m2, v2,
        out, nullptr, nullptr);

    // 4) tail (also reclaims the W2 scratch region)
    const long long tail = (long long)out_size - (long long)H_ELEMS;
    if (tail > 0) {
        const int mode = (tail - POS_ELEMS >= 2 * M_ROWS) ? 1 : 0;
        tail_kernel<<<(POS_ELEMS + M_ROWS + 255) / 256, 256, 0, stream>>>(
            pos_skip, out + H_ELEMS, mode);
    }
    (void)in_sizes; (void)n_in; (void)ws_size; (void)d_in;
}

// Round 4
// 537.367 us; speedup vs baseline: 1.9869x; 1.3717x over previous
//
#include <hip/hip_runtime.h>
#include <hip/hip_bf16.h>
#include <cstddef>
#include <cstdint>

// Problem constants
#define NB 16
#define NC 1024
#define NF 4096
#define CIN 256
#define CSKIP 128
#define HW_ 512
#define K1 (CIN + CSKIP)                  // 384
#define M_ROWS (NB * NF)                  // 65536
#define H_ELEMS ((size_t)M_ROWS * HW_)    // 33554432
#define POS_ELEMS (M_ROWS * 3)            // 196608

#define QB 64      // queries per kNN block
#define PARTS 4    // candidate quarters per query

typedef __attribute__((ext_vector_type(8))) short bf16x8;
typedef __attribute__((ext_vector_type(4))) float f32x4;

__device__ __forceinline__ unsigned short f2bf(float f) {
    union { __hip_bfloat16 h; unsigned short u; } cv;
    cv.h = __float2bfloat16(f);
    return cv.u;
}
__device__ __forceinline__ float bf2f(unsigned short u) {
    union { __hip_bfloat16 h; unsigned short u; } cv;
    cv.u = u;
    return __bfloat162float(cv.h);
}
__device__ __forceinline__ void split2(float v, unsigned short& hi, unsigned short& lo) {
    hi = f2bf(v);
    lo = f2bf(v - bf2f(hi));
}

#define GLOAD_LDS(gsrc, ldst)                                                            \
    __builtin_amdgcn_global_load_lds((const __attribute__((address_space(1))) void*)(gsrc), \
                                     (__attribute__((address_space(3))) void*)(ldst), 16, 0, 0)

// ---------------------------------------------------------------------------
// Kernel 1 (v2): kNN (K=3) + inverse-distance interpolation.
// 1024 blocks: each = (cloud, 64-query chunk). 4 waves = 4 candidate quarters
// per query. Inner loop: 1 uniform ds_read_b128 + branchless top-3 insert
// (min/med3 for values, strict-< cndmask for indices => stable ties like
// top_k). Partials merged in LDS; exact d^2 recomputed for the 3 winners.
// Output: split bf16 planes, columns 0..255 of A1 (row stride K1).
// ---------------------------------------------------------------------------
__launch_bounds__(256)
__global__ void knn_interp_kernel(const float* __restrict__ x,
                                  const float* __restrict__ pos,
                                  const float* __restrict__ pos_skip,
                                  unsigned short* __restrict__ Ahi,
                                  unsigned short* __restrict__ Alo)
{
    __shared__ float4 sp4[NC];                 // px,py,pz,|p|^2  (16 KB)
    __shared__ float  s_b[QB * PARTS * 3];     // partial best d2
    __shared__ int    s_i[QB * PARTS * 3];     // partial best idx
    __shared__ int    s_idx[QB * 3];
    __shared__ float  s_w[QB * 3];

    const int tid   = threadIdx.x;
    const int cloud = blockIdx.x >> 6;         // 64 chunks per cloud
    const int chunk = blockIdx.x & 63;

    // stage positions + |p|^2
    const float* pbase = pos + (size_t)cloud * NC * 3;
    for (int j = tid; j < NC; j += 256) {
        const float px = pbase[3 * j + 0];
        const float py = pbase[3 * j + 1];
        const float pz = pbase[3 * j + 2];
        sp4[j] = make_float4(px, py, pz, px * px + py * py + pz * pz);
    }
    __syncthreads();

    const int q    = tid & (QB - 1);
    const int part = tid >> 6;                 // == wave id
    const float* qp = pos_skip + ((size_t)cloud * NF + chunk * QB + q) * 3;
    const float qx = qp[0], qy = qp[1], qz = qp[2];
    const float ax = -2.f * qx, ay = -2.f * qy, az = -2.f * qz;
    const float qq = qx * qx + qy * qy + qz * qz;

    float b0 = 1e30f, b1 = 1e30f, b2 = 1e30f;
    int   i0 = 0,     i1 = 0,     i2 = 0;
    const int jbase = part * (NC / PARTS);
#pragma unroll 4
    for (int jj = 0; jj < NC / PARTS; ++jj) {
        const int j = jbase + jj;
        const float4 p = sp4[j];               // uniform addr -> broadcast
        const float d = fmaf(ax, p.x, fmaf(ay, p.y, fmaf(az, p.z, p.w))) + qq;
        const bool c0 = d < b0, c1 = d < b1, c2 = d < b2;
        const float nb0 = fminf(b0, d);
        const float nb1 = __builtin_amdgcn_fmed3f(b0, b1, d);
        const float nb2 = __builtin_amdgcn_fmed3f(b1, b2, d);
        const int ni0 = c0 ? j : i0;
        const int ni1 = c0 ? i0 : (c1 ? j : i1);
        const int ni2 = c1 ? i1 : (c2 ? j : i2);
        b0 = nb0; b1 = nb1; b2 = nb2;
        i0 = ni0; i1 = ni1; i2 = ni2;
    }
    {
        const int pb = (q * PARTS + part) * 3;
        s_b[pb + 0] = b0; s_b[pb + 1] = b1; s_b[pb + 2] = b2;
        s_i[pb + 0] = i0; s_i[pb + 1] = i1; s_i[pb + 2] = i2;
    }
    __syncthreads();

    // merge 4 partials (wave 0 only; lane == its query; parts are in
    // ascending index order so strict-< keeps top_k's stable tie-break)
    if (tid < QB) {
        const int base = tid * PARTS * 3;
        float m0 = s_b[base + 0], m1 = s_b[base + 1], m2 = s_b[base + 2];
        int   a0 = s_i[base + 0], a1 = s_i[base + 1], a2 = s_i[base + 2];
#pragma unroll
        for (int p = 1; p < PARTS; ++p) {
#pragma unroll
            for (int s = 0; s < 3; ++s) {
                const float d = s_b[base + p * 3 + s];
                const int   j = s_i[base + p * 3 + s];
                const bool c0 = d < m0, c1 = d < m1, c2 = d < m2;
                const float n0 = fminf(m0, d);
                const float n1 = __builtin_amdgcn_fmed3f(m0, m1, d);
                const float n2 = __builtin_amdgcn_fmed3f(m1, m2, d);
                const int e0 = c0 ? j : a0;
                const int e1 = c0 ? a0 : (c1 ? j : a1);
                const int e2 = c1 ? a1 : (c2 ? j : a2);
                m0 = n0; m1 = n1; m2 = n2;
                a0 = e0; a1 = e1; a2 = e2;
            }
        }
        // exact d^2 (reference formula) for the winners
        const int id[3] = {a0, a1, a2};
        float w[3], tw = 0.f;
#pragma unroll
        for (int s = 0; s < 3; ++s) {
            const float4 p = sp4[id[s]];
            const float dx = qx - p.x, dy = qy - p.y, dz = qz - p.z;
            const float d2 = fmaf(dx, dx, fmaf(dy, dy, dz * dz));
            w[s] = 1.f / fmaxf(d2, 1e-16f);
            tw += w[s];
        }
        const float winv = 1.f / tw;
#pragma unroll
        for (int s = 0; s < 3; ++s) {
            s_idx[tid * 3 + s] = id[s];
            s_w[tid * 3 + s]   = w[s] * winv;
        }
    }
    __syncthreads();

    // gather: wave-cooperative, 64 lanes x float4 = 256 channels per row
    const int wave = tid >> 6, lane = tid & 63;
    const float* xc = x + (size_t)cloud * NC * CIN;
    const size_t rowbase = (size_t)cloud * NF + chunk * QB;
    for (int qq2 = wave; qq2 < QB; qq2 += 4) {
        const int   j0 = s_idx[qq2 * 3 + 0], j1 = s_idx[qq2 * 3 + 1], j2 = s_idx[qq2 * 3 + 2];
        const float u0 = s_w[qq2 * 3 + 0],   u1 = s_w[qq2 * 3 + 1],   u2 = s_w[qq2 * 3 + 2];
        const float4 f0 = ((const float4*)(xc + (size_t)j0 * CIN))[lane];
        const float4 f1 = ((const float4*)(xc + (size_t)j1 * CIN))[lane];
        const float4 f2 = ((const float4*)(xc + (size_t)j2 * CIN))[lane];
        float o[4];
        o[0] = u0 * f0.x + u1 * f1.x + u2 * f2.x;
        o[1] = u0 * f0.y + u1 * f1.y + u2 * f2.y;
        o[2] = u0 * f0.z + u1 * f1.z + u2 * f2.z;
        o[3] = u0 * f0.w + u1 * f1.w + u2 * f2.w;
        unsigned short h[4], l[4];
#pragma unroll
        for (int c = 0; c < 4; ++c) split2(o[c], h[c], l[c]);
        uint2 hv, lv;
        hv.x = (unsigned)h[0] | ((unsigned)h[1] << 16);
        hv.y = (unsigned)h[2] | ((unsigned)h[3] << 16);
        lv.x = (unsigned)l[0] | ((unsigned)l[1] << 16);
        lv.y = (unsigned)l[2] | ((unsigned)l[3] << 16);
        const size_t ro = (rowbase + qq2) * K1;
        ((uint2*)(Ahi + ro))[lane] = hv;
        ((uint2*)(Alo + ro))[lane] = lv;
    }
}

// ---------------------------------------------------------------------------
// Kernel 2: x_skip [M][128] f32 -> split planes at columns 256..383 of A1.
// ---------------------------------------------------------------------------
__launch_bounds__(256)
__global__ void conv_skip_kernel(const float* __restrict__ xs,
                                 unsigned short* __restrict__ Ahi,
                                 unsigned short* __restrict__ Alo)
{
    const int idx = blockIdx.x * 256 + threadIdx.x;
    const int row = idx >> 5;
    const int c4  = idx & 31;
    const float4 v = ((const float4*)(xs + (size_t)row * CSKIP))[c4];
    const float o[4] = {v.x, v.y, v.z, v.w};
    unsigned short h[4], l[4];
#pragma unroll
    for (int c = 0; c < 4; ++c) split2(o[c], h[c], l[c]);
    uint2 hv, lv;
    hv.x = (unsigned)h[0] | ((unsigned)h[1] << 16);
    hv.y = (unsigned)h[2] | ((unsigned)h[3] << 16);
    lv.x = (unsigned)l[0] | ((unsigned)l[1] << 16);
    lv.y = (unsigned)l[2] | ((unsigned)l[3] << 16);
    const size_t off = (size_t)row * K1 + CIN + c4 * 4;
    *(uint2*)(Ahi + off) = hv;
    *(uint2*)(Alo + off) = lv;
}

// ---------------------------------------------------------------------------
// Kernel 3: weight transpose + split: w [Kd][512] f32 -> WT planes [512][Kd].
// ---------------------------------------------------------------------------
__launch_bounds__(256)
__global__ void conv_w_kernel(const float* __restrict__ w,
                              unsigned short* __restrict__ WhiT,
                              unsigned short* __restrict__ WloT, int Kd)
{
    const int idx = blockIdx.x * 256 + threadIdx.x;
    if (idx >= Kd * 512) return;
    const int k = idx >> 9;
    const int n = idx & 511;
    const float v = w[(size_t)k * 512 + n];
    unsigned short h, l;
    split2(v, h, l);
    WhiT[(size_t)n * Kd + k] = h;
    WloT[(size_t)n * Kd + k] = l;
}

// ---------------------------------------------------------------------------
// Kernel 4: bf16 split NT-GEMM, MFMA 16x16x32, fused bias->ReLU->BN.
// K' = 3K regions: (Ahi,Whi), (Ahi,Wlo), (Alo,Whi).
// 1D grid of 2048 with bijective XCD swizzle: the 4 N-blocks of one M-panel
// land consecutively on the SAME XCD -> A panel fetched once from HBM,
// 3x from that XCD's L2.
// ---------------------------------------------------------------------------
template <bool SPLIT_OUT>
__launch_bounds__(256)
__global__ void gemm_bf3s(const unsigned short* __restrict__ Ahi,
                          const unsigned short* __restrict__ Alo,
                          const unsigned short* __restrict__ Whi,   // [512][K]
                          const unsigned short* __restrict__ Wlo,
                          int K,
                          const float* __restrict__ bias,
                          const float* __restrict__ gamma,
                          const float* __restrict__ beta,
                          const float* __restrict__ mean,
                          const float* __restrict__ var,
                          float* __restrict__ Cf,
                          unsigned short* __restrict__ Chi,
                          unsigned short* __restrict__ Clo)
{
    __shared__ alignas(16) unsigned short As[2][128 * 32];
    __shared__ alignas(16) unsigned short Bs[2][128 * 32];

    // XCD swizzle: hw assigns xcd = blockIdx.x % 8 round-robin.
    const int bid  = blockIdx.x;
    const int xcd  = bid & 7;
    const int slot = bid >> 3;
    const int bx   = slot & 3;                 // N-block (grid.x == 4)
    const int by   = xcd + (slot >> 2) * 8;    // M-block, same-XCD contiguous
    const int bm   = by * 128;
    const int bn   = bx * 128;

    const int tid  = threadIdx.x;
    const int lane = tid & 63;
    const int wv   = tid >> 6;
    const int wr   = wv >> 1;
    const int wc   = wv & 1;

    const int sr  = lane >> 2;
    const int sgp = lane & 3;

    f32x4 acc[4][4];
#pragma unroll
    for (int i = 0; i < 4; ++i)
#pragma unroll
        for (int j = 0; j < 4; ++j) acc[i][j] = (f32x4){0.f, 0.f, 0.f, 0.f};

    const int NT = 3 * K / 32;

    auto stage = [&](int buf, int t) {
        const int kp = t * 32;
        const int region = kp / K;
        const int kk = kp - region * K;
        const unsigned short* Ap = (region < 2) ? Ahi : Alo;
        const unsigned short* Bp = (region == 1) ? Wlo : Whi;
#pragma unroll
        for (int i = 0; i < 2; ++i) {
            const int r = wv * 32 + i * 16 + sr;
            const int g = sgp ^ ((r >> 1) & 3);
            GLOAD_LDS(Ap + (size_t)(bm + r) * K + kk + g * 8,
                      &As[buf][(wv * 32 + i * 16) * 32]);
        }
#pragma unroll
        for (int i = 0; i < 2; ++i) {
            const int r = wv * 32 + i * 16 + sr;
            const int g = sgp ^ ((r >> 1) & 3);
            GLOAD_LDS(Bp + (size_t)(bn + r) * K + kk + g * 8,
                      &Bs[buf][(wv * 32 + i * 16) * 32]);
        }
    };

    int cur = 0;
    stage(0, 0);
    for (int t = 0; t < NT; ++t) {
        __syncthreads();
        if (t + 1 < NT) stage(cur ^ 1, t + 1);

        bf16x8 af[4], bw[4];
#pragma unroll
        for (int i = 0; i < 4; ++i) {
            const int r  = wr * 64 + i * 16 + (lane & 15);
            const int ga = (lane >> 4) ^ ((r >> 1) & 3);
            af[i] = *(const bf16x8*)&As[cur][r * 32 + ga * 8];
            const int c  = wc * 64 + i * 16 + (lane & 15);
            const int gb = (lane >> 4) ^ ((c >> 1) & 3);
            bw[i] = *(const bf16x8*)&Bs[cur][c * 32 + gb * 8];
        }
#pragma unroll
        for (int i = 0; i < 4; ++i)
#pragma unroll
            for (int j = 0; j < 4; ++j)
                acc[i][j] = __builtin_amdgcn_mfma_f32_16x16x32_bf16(af[i], bw[j], acc[i][j], 0, 0, 0);
        cur ^= 1;
    }

    const int lc  = lane & 15;
    const int lr4 = (lane >> 4) * 4;
#pragma unroll
    for (int j = 0; j < 4; ++j) {
        const int col = bn + wc * 64 + j * 16 + lc;
        const float s  = gamma[col] / sqrtf(var[col] + 1e-5f);
        const float sh = beta[col] - mean[col] * s;
        const float bb = bias[col];
#pragma unroll
        for (int i = 0; i < 4; ++i) {
            const f32x4 v = acc[i][j];
#pragma unroll
            for (int qreg = 0; qreg < 4; ++qreg) {
                const int row = bm + wr * 64 + i * 16 + lr4 + qreg;
                const float val = fmaxf(v[qreg] + bb, 0.f) * s + sh;
                const size_t off = (size_t)row * HW_ + col;
                if (SPLIT_OUT) {
                    unsigned short h, l;
                    split2(val, h, l);
                    Chi[off] = h;
                    Clo[off] = l;
                } else {
                    Cf[off] = val;
                }
            }
        }
    }
}

// ---------------------------------------------------------------------------
// Kernel 5: tail outputs (pos_skip copy + batch ids). Runs LAST — also
// reclaims the W2^T scratch parked in the tail region.
// ---------------------------------------------------------------------------
__launch_bounds__(256)
__global__ void tail_kernel(const float* __restrict__ pos_skip,
                            float* __restrict__ outp, int mode)
{
    const int i = blockIdx.x * 256 + threadIdx.x;
    if (i < POS_ELEMS) outp[i] = pos_skip[i];
    const int bi = i - POS_ELEMS;
    if (bi >= 0 && bi < M_ROWS) {
        if (mode == 0) {
            outp[POS_ELEMS + bi] = (float)(bi >> 12);
        } else {
            ((unsigned long long*)(outp + POS_ELEMS))[bi] = (unsigned long long)(bi >> 12);
        }
    }
}

// ---------------------------------------------------------------------------
extern "C" void kernel_launch(void* const* d_in, const int* in_sizes, int n_in,
                              void* d_out, int out_size, void* d_ws, size_t ws_size,
                              hipStream_t stream)
{
    const float* x        = (const float*)d_in[0];
    const float* pos      = (const float*)d_in[1];
    const float* x_skip   = (const float*)d_in[3];
    const float* pos_skip = (const float*)d_in[4];
    const float* w1  = (const float*)d_in[6];
    const float* b1  = (const float*)d_in[7];
    const float* g1  = (const float*)d_in[8];
    const float* be1 = (const float*)d_in[9];
    const float* m1  = (const float*)d_in[10];
    const float* v1  = (const float*)d_in[11];
    const float* w2  = (const float*)d_in[12];
    const float* b2  = (const float*)d_in[13];
    const float* g2  = (const float*)d_in[14];
    const float* be2 = (const float*)d_in[15];
    const float* m2  = (const float*)d_in[16];
    const float* v2  = (const float*)d_in[17];

    float* out = (float*)d_out;

    unsigned short* A1hi = (unsigned short*)d_out;
    unsigned short* A1lo = A1hi + (size_t)M_ROWS * K1;
    unsigned short* W1hi = A1lo + (size_t)M_ROWS * K1;
    unsigned short* W1lo = W1hi + (size_t)512 * K1;
    unsigned short* W2hi = (unsigned short*)(out + H_ELEMS);
    unsigned short* W2lo = W2hi + (size_t)512 * 512;
    unsigned short* h1hi = (unsigned short*)d_ws;
    unsigned short* h1lo = h1hi + H_ELEMS;

    // 1) producers
    knn_interp_kernel<<<NB * (NF / QB), 256, 0, stream>>>(x, pos, pos_skip, A1hi, A1lo);
    conv_skip_kernel<<<M_ROWS * 32 / 256, 256, 0, stream>>>(x_skip, A1hi, A1lo);
    conv_w_kernel<<<(K1 * 512 + 255) / 256, 256, 0, stream>>>(w1, W1hi, W1lo, K1);
    conv_w_kernel<<<(512 * 512 + 255) / 256, 256, 0, stream>>>(w2, W2hi, W2lo, 512);

    // 2) Layer 1: [65536 x 384] @ [384 x 512] -> split h1 planes
    gemm_bf3s<true><<<dim3(4 * (M_ROWS / 128)), 256, 0, stream>>>(
        A1hi, A1lo, W1hi, W1lo, K1, b1, g1, be1, m1, v1,
        nullptr, h1hi, h1lo);

    // 3) Layer 2: [65536 x 512] @ [512 x 512] -> f32 out
    gemm_bf3s<false><<<dim3(4 * (M_ROWS / 128)), 256, 0, stream>>>(
        h1hi, h1lo, W2hi, W2lo, HW_, b2, g2, be2, m2, v2,
        out, nullptr, nullptr);

    // 4) tail
    const long long tail = (long long)out_size - (long long)H_ELEMS;
    if (tail > 0) {
        const int mode = (tail - POS_ELEMS >= 2 * M_ROWS) ? 1 : 0;
        tail_kernel<<<(POS_ELEMS + M_ROWS + 255) / 256, 256, 0, stream>>>(
            pos_skip, out + H_ELEMS, mode);
    }
    (void)in_sizes; (void)n_in; (void)ws_size; (void)d_in;
}

// Round 5
// 423.942 us; speedup vs baseline: 2.5185x; 1.2676x over previous
//
#include <hip/hip_runtime.h>
#include <hip/hip_bf16.h>
#include <cstddef>
#include <cstdint>

// Problem constants
#define NB 16
#define NC 1024
#define NF 4096
#define CIN 256
#define CSKIP 128
#define HW_ 512
#define K1 (CIN + CSKIP)                  // 384
#define M_ROWS (NB * NF)                  // 65536
#define H_ELEMS ((size_t)M_ROWS * HW_)    // 33554432
#define POS_ELEMS (M_ROWS * 3)            // 196608

#define QB 64      // queries per kNN block
#define PARTS 4    // candidate quarters per query

typedef __attribute__((ext_vector_type(8))) short bf16x8;
typedef __attribute__((ext_vector_type(4))) float f32x4;
typedef __attribute__((ext_vector_type(4))) unsigned int u32x4;

__device__ __forceinline__ unsigned short f2bf(float f) {
    union { __hip_bfloat16 h; unsigned short u; } cv;
    cv.h = __float2bfloat16(f);
    return cv.u;
}
__device__ __forceinline__ float bf2f(unsigned short u) {
    union { __hip_bfloat16 h; unsigned short u; } cv;
    cv.u = u;
    return __bfloat162float(cv.h);
}
__device__ __forceinline__ void split2(float v, unsigned short& hi, unsigned short& lo) {
    hi = f2bf(v);
    lo = f2bf(v - bf2f(hi));
}

#define GLOAD_LDS(gsrc, ldst)                                                            \
    __builtin_amdgcn_global_load_lds((const __attribute__((address_space(1))) void*)(gsrc), \
                                     (__attribute__((address_space(3))) void*)(ldst), 16, 0, 0)

// ---------------------------------------------------------------------------
// Kernel 1: kNN (K=3) + inverse-distance interpolation (unchanged this round).
// ---------------------------------------------------------------------------
__launch_bounds__(256)
__global__ void knn_interp_kernel(const float* __restrict__ x,
                                  const float* __restrict__ pos,
                                  const float* __restrict__ pos_skip,
                                  unsigned short* __restrict__ Ahi,
                                  unsigned short* __restrict__ Alo)
{
    __shared__ float4 sp4[NC];
    __shared__ float  s_b[QB * PARTS * 3];
    __shared__ int    s_i[QB * PARTS * 3];
    __shared__ int    s_idx[QB * 3];
    __shared__ float  s_w[QB * 3];

    const int tid   = threadIdx.x;
    const int cloud = blockIdx.x >> 6;
    const int chunk = blockIdx.x & 63;

    const float* pbase = pos + (size_t)cloud * NC * 3;
    for (int j = tid; j < NC; j += 256) {
        const float px = pbase[3 * j + 0];
        const float py = pbase[3 * j + 1];
        const float pz = pbase[3 * j + 2];
        sp4[j] = make_float4(px, py, pz, px * px + py * py + pz * pz);
    }
    __syncthreads();

    const int q    = tid & (QB - 1);
    const int part = tid >> 6;
    const float* qp = pos_skip + ((size_t)cloud * NF + chunk * QB + q) * 3;
    const float qx = qp[0], qy = qp[1], qz = qp[2];
    const float ax = -2.f * qx, ay = -2.f * qy, az = -2.f * qz;
    const float qq = qx * qx + qy * qy + qz * qz;

    float b0 = 1e30f, b1 = 1e30f, b2 = 1e30f;
    int   i0 = 0,     i1 = 0,     i2 = 0;
    const int jbase = part * (NC / PARTS);
#pragma unroll 4
    for (int jj = 0; jj < NC / PARTS; ++jj) {
        const int j = jbase + jj;
        const float4 p = sp4[j];
        const float d = fmaf(ax, p.x, fmaf(ay, p.y, fmaf(az, p.z, p.w))) + qq;
        const bool c0 = d < b0, c1 = d < b1, c2 = d < b2;
        const float nb0 = fminf(b0, d);
        const float nb1 = __builtin_amdgcn_fmed3f(b0, b1, d);
        const float nb2 = __builtin_amdgcn_fmed3f(b1, b2, d);
        const int ni0 = c0 ? j : i0;
        const int ni1 = c0 ? i0 : (c1 ? j : i1);
        const int ni2 = c1 ? i1 : (c2 ? j : i2);
        b0 = nb0; b1 = nb1; b2 = nb2;
        i0 = ni0; i1 = ni1; i2 = ni2;
    }
    {
        const int pb = (q * PARTS + part) * 3;
        s_b[pb + 0] = b0; s_b[pb + 1] = b1; s_b[pb + 2] = b2;
        s_i[pb + 0] = i0; s_i[pb + 1] = i1; s_i[pb + 2] = i2;
    }
    __syncthreads();

    if (tid < QB) {
        const int base = tid * PARTS * 3;
        float m0 = s_b[base + 0], m1 = s_b[base + 1], m2 = s_b[base + 2];
        int   a0 = s_i[base + 0], a1 = s_i[base + 1], a2 = s_i[base + 2];
#pragma unroll
        for (int p = 1; p < PARTS; ++p) {
#pragma unroll
            for (int s = 0; s < 3; ++s) {
                const float d = s_b[base + p * 3 + s];
                const int   j = s_i[base + p * 3 + s];
                const bool c0 = d < m0, c1 = d < m1, c2 = d < m2;
                const float n0 = fminf(m0, d);
                const float n1 = __builtin_amdgcn_fmed3f(m0, m1, d);
                const float n2 = __builtin_amdgcn_fmed3f(m1, m2, d);
                const int e0 = c0 ? j : a0;
                const int e1 = c0 ? a0 : (c1 ? j : a1);
                const int e2 = c1 ? a1 : (c2 ? j : a2);
                m0 = n0; m1 = n1; m2 = n2;
                a0 = e0; a1 = e1; a2 = e2;
            }
        }
        const int id[3] = {a0, a1, a2};
        float w[3], tw = 0.f;
#pragma unroll
        for (int s = 0; s < 3; ++s) {
            const float4 p = sp4[id[s]];
            const float dx = qx - p.x, dy = qy - p.y, dz = qz - p.z;
            const float d2 = fmaf(dx, dx, fmaf(dy, dy, dz * dz));
            w[s] = 1.f / fmaxf(d2, 1e-16f);
            tw += w[s];
        }
        const float winv = 1.f / tw;
#pragma unroll
        for (int s = 0; s < 3; ++s) {
            s_idx[tid * 3 + s] = id[s];
            s_w[tid * 3 + s]   = w[s] * winv;
        }
    }
    __syncthreads();

    const int wave = tid >> 6, lane = tid & 63;
    const float* xc = x + (size_t)cloud * NC * CIN;
    const size_t rowbase = (size_t)cloud * NF + chunk * QB;
    for (int qq2 = wave; qq2 < QB; qq2 += 4) {
        const int   j0 = s_idx[qq2 * 3 + 0], j1 = s_idx[qq2 * 3 + 1], j2 = s_idx[qq2 * 3 + 2];
        const float u0 = s_w[qq2 * 3 + 0],   u1 = s_w[qq2 * 3 + 1],   u2 = s_w[qq2 * 3 + 2];
        const float4 f0 = ((const float4*)(xc + (size_t)j0 * CIN))[lane];
        const float4 f1 = ((const float4*)(xc + (size_t)j1 * CIN))[lane];
        const float4 f2 = ((const float4*)(xc + (size_t)j2 * CIN))[lane];
        float o[4];
        o[0] = u0 * f0.x + u1 * f1.x + u2 * f2.x;
        o[1] = u0 * f0.y + u1 * f1.y + u2 * f2.y;
        o[2] = u0 * f0.z + u1 * f1.z + u2 * f2.z;
        o[3] = u0 * f0.w + u1 * f1.w + u2 * f2.w;
        unsigned short h[4], l[4];
#pragma unroll
        for (int c = 0; c < 4; ++c) split2(o[c], h[c], l[c]);
        uint2 hv, lv;
        hv.x = (unsigned)h[0] | ((unsigned)h[1] << 16);
        hv.y = (unsigned)h[2] | ((unsigned)h[3] << 16);
        lv.x = (unsigned)l[0] | ((unsigned)l[1] << 16);
        lv.y = (unsigned)l[2] | ((unsigned)l[3] << 16);
        const size_t ro = (rowbase + qq2) * K1;
        ((uint2*)(Ahi + ro))[lane] = hv;
        ((uint2*)(Alo + ro))[lane] = lv;
    }
}

// ---------------------------------------------------------------------------
// Kernel 2: x_skip -> split planes at columns 256..383 of A1.
// ---------------------------------------------------------------------------
__launch_bounds__(256)
__global__ void conv_skip_kernel(const float* __restrict__ xs,
                                 unsigned short* __restrict__ Ahi,
                                 unsigned short* __restrict__ Alo)
{
    const int idx = blockIdx.x * 256 + threadIdx.x;
    const int row = idx >> 5;
    const int c4  = idx & 31;
    const float4 v = ((const float4*)(xs + (size_t)row * CSKIP))[c4];
    const float o[4] = {v.x, v.y, v.z, v.w};
    unsigned short h[4], l[4];
#pragma unroll
    for (int c = 0; c < 4; ++c) split2(o[c], h[c], l[c]);
    uint2 hv, lv;
    hv.x = (unsigned)h[0] | ((unsigned)h[1] << 16);
    hv.y = (unsigned)h[2] | ((unsigned)h[3] << 16);
    lv.x = (unsigned)l[0] | ((unsigned)l[1] << 16);
    lv.y = (unsigned)l[2] | ((unsigned)l[3] << 16);
    const size_t off = (size_t)row * K1 + CIN + c4 * 4;
    *(uint2*)(Ahi + off) = hv;
    *(uint2*)(Alo + off) = lv;
}

// ---------------------------------------------------------------------------
// Kernel 3: weight transpose + split -> WT planes [512][Kd].
// ---------------------------------------------------------------------------
__launch_bounds__(256)
__global__ void conv_w_kernel(const float* __restrict__ w,
                              unsigned short* __restrict__ WhiT,
                              unsigned short* __restrict__ WloT, int Kd)
{
    const int idx = blockIdx.x * 256 + threadIdx.x;
    if (idx >= Kd * 512) return;
    const int k = idx >> 9;
    const int n = idx & 511;
    const float v = w[(size_t)k * 512 + n];
    unsigned short h, l;
    split2(v, h, l);
    WhiT[(size_t)n * Kd + k] = h;
    WloT[(size_t)n * Kd + k] = l;
}

// ---------------------------------------------------------------------------
// Kernel 4 (v2): fused-region bf16 split NT-GEMM + LDS-staged epilogue.
// Per K-tile (32 real K): stage {Ahi, Alo, Whi, Wlo} (4 x 8KB, dbuf = 64KB),
// one barrier-pair, 48 MFMA (hh + hl + lh), fragments reused in registers.
// Epilogue: acc -> packed-u32 LDS C-tile (XOR-granule swizzle, conflict-free
// writes) -> coalesced global stores (256B segments split / 16B f32x4).
// ---------------------------------------------------------------------------
#define AHI_OFF 0
#define ALO_OFF 16384
#define WHI_OFF 32768
#define WLO_OFF 49152

__device__ __forceinline__ int cswz(int row) {
    return (((row >> 2) & 3) << 2) ^ (((row >> 3) & 1) << 1) ^ ((row >> 4) & 1);
}

template <bool SPLIT_OUT>
__launch_bounds__(256, 2)
__global__ void gemm_bf3s(const unsigned short* __restrict__ Ahi,
                          const unsigned short* __restrict__ Alo,
                          const unsigned short* __restrict__ Whi,   // [512][K]
                          const unsigned short* __restrict__ Wlo,
                          int K,
                          const float* __restrict__ bias,
                          const float* __restrict__ gamma,
                          const float* __restrict__ beta,
                          const float* __restrict__ mean,
                          const float* __restrict__ var,
                          float* __restrict__ Cf,
                          unsigned short* __restrict__ Chi,
                          unsigned short* __restrict__ Clo)
{
    __shared__ alignas(16) unsigned char smem[65536];

    // XCD swizzle: 4 N-blocks of an M-panel land consecutively on one XCD.
    const int bid  = blockIdx.x;
    const int xcd  = bid & 7;
    const int slot = bid >> 3;
    const int bx   = slot & 3;
    const int by   = xcd + (slot >> 2) * 8;
    const int bm   = by * 128;
    const int bn   = bx * 128;

    const int tid  = threadIdx.x;
    const int lane = tid & 63;
    const int wv   = tid >> 6;
    const int wr   = wv >> 1;
    const int wc   = wv & 1;

    const int sr  = lane >> 2;      // staging row within 16-row chunk
    const int sgp = lane & 3;       // staging physical granule

    f32x4 acc[4][4];
#pragma unroll
    for (int i = 0; i < 4; ++i)
#pragma unroll
        for (int j = 0; j < 4; ++j) acc[i][j] = (f32x4){0.f, 0.f, 0.f, 0.f};

    auto stage = [&](int buf, int kk) {
#pragma unroll
        for (int i = 0; i < 2; ++i) {
            const int rl = (wv * 2 + i) * 16 + sr;                  // 0..127
            const int g  = sgp ^ ((rl >> 1) & 3);
            const unsigned dst = (wv * 2 + i) * 1024 + buf * 8192;
            const size_t roA = (size_t)(bm + rl) * K + kk + g * 8;
            GLOAD_LDS(Ahi + roA, smem + AHI_OFF + dst);
            GLOAD_LDS(Alo + roA, smem + ALO_OFF + dst);
            const size_t roW = (size_t)(bn + rl) * K + kk + g * 8;
            GLOAD_LDS(Whi + roW, smem + WHI_OFF + dst);
            GLOAD_LDS(Wlo + roW, smem + WLO_OFF + dst);
        }
    };

    int cur = 0;
    stage(0, 0);
    const int NT = K / 32;
    for (int t = 0; t < NT; ++t) {
        __syncthreads();                       // drains vmcnt -> tile t visible
        if (t + 1 < NT) stage(cur ^ 1, (t + 1) * 32);

        const unsigned short* sAh = (const unsigned short*)(smem + AHI_OFF + cur * 8192);
        const unsigned short* sAl = (const unsigned short*)(smem + ALO_OFF + cur * 8192);
        const unsigned short* sWh = (const unsigned short*)(smem + WHI_OFF + cur * 8192);
        const unsigned short* sWl = (const unsigned short*)(smem + WLO_OFF + cur * 8192);

        bf16x8 ah[4], al[4], wh[4], wl[4];
#pragma unroll
        for (int i = 0; i < 4; ++i) {
            const int r  = wr * 64 + i * 16 + (lane & 15);
            const int ga = (lane >> 4) ^ ((r >> 1) & 3);
            ah[i] = *(const bf16x8*)(sAh + r * 32 + ga * 8);
            al[i] = *(const bf16x8*)(sAl + r * 32 + ga * 8);
            const int c  = wc * 64 + i * 16 + (lane & 15);
            const int gb = (lane >> 4) ^ ((c >> 1) & 3);
            wh[i] = *(const bf16x8*)(sWh + c * 32 + gb * 8);
            wl[i] = *(const bf16x8*)(sWl + c * 32 + gb * 8);
        }
#pragma unroll
        for (int i = 0; i < 4; ++i)
#pragma unroll
            for (int j = 0; j < 4; ++j)
                acc[i][j] = __builtin_amdgcn_mfma_f32_16x16x32_bf16(ah[i], wh[j], acc[i][j], 0, 0, 0);
#pragma unroll
        for (int i = 0; i < 4; ++i)
#pragma unroll
            for (int j = 0; j < 4; ++j)
                acc[i][j] = __builtin_amdgcn_mfma_f32_16x16x32_bf16(ah[i], wl[j], acc[i][j], 0, 0, 0);
#pragma unroll
        for (int i = 0; i < 4; ++i)
#pragma unroll
            for (int j = 0; j < 4; ++j)
                acc[i][j] = __builtin_amdgcn_mfma_f32_16x16x32_bf16(al[i], wh[j], acc[i][j], 0, 0, 0);
        cur ^= 1;
    }

    // ---- epilogue: BN -> packed u32 LDS C-tile -> coalesced global stores
    __syncthreads();                            // all ds_reads of last tile done
    unsigned int* sC = (unsigned int*)smem;     // [128][128] u32 (64KB)

    const int lc  = lane & 15;
    const int lr4 = (lane >> 4) * 4;
#pragma unroll
    for (int j = 0; j < 4; ++j) {
        const int col  = wc * 64 + j * 16 + lc;            // tile-local col
        const int colg = bn + col;
        const float s  = gamma[colg] / sqrtf(var[colg] + 1e-5f);
        const float sh = beta[colg] - mean[colg] * s;
        const float bb = bias[colg];
        const int g    = col >> 2;
#pragma unroll
        for (int i = 0; i < 4; ++i) {
            const f32x4 v = acc[i][j];
#pragma unroll
            for (int q = 0; q < 4; ++q) {
                const int row = wr * 64 + i * 16 + lr4 + q;
                const float val = fmaxf(v[q] + bb, 0.f) * s + sh;
                unsigned u;
                if (SPLIT_OUT) {
                    unsigned short h, l;
                    split2(val, h, l);
                    u = (unsigned)h | ((unsigned)l << 16);
                } else {
                    u = __float_as_uint(val);
                }
                sC[row * 128 + ((g ^ cswz(row)) << 2) + (col & 3)] = u;
            }
        }
    }
    __syncthreads();

    // reader: per iter, 2 rows x 32 granules -> 256B contiguous per row-plane
#pragma unroll
    for (int it = 0; it < 16; ++it) {
        const int row = wv * 32 + it * 2 + (lane >> 5);
        const int g   = lane & 31;
        const u32x4 v = *(const u32x4*)(sC + row * 128 + ((g ^ cswz(row)) << 2));
        const size_t rg = (size_t)(bm + row) * HW_ + bn + g * 4;
        if (SPLIT_OUT) {
            uint2 hv, lv;
            hv.x = (v[0] & 0xffffu) | (v[1] << 16);
            hv.y = (v[2] & 0xffffu) | (v[3] << 16);
            lv.x = (v[0] >> 16) | (v[1] & 0xffff0000u);
            lv.y = (v[2] >> 16) | (v[3] & 0xffff0000u);
            *(uint2*)(Chi + rg) = hv;
            *(uint2*)(Clo + rg) = lv;
        } else {
            *(u32x4*)((unsigned int*)Cf + rg) = v;
        }
    }
}

// ---------------------------------------------------------------------------
// Kernel 5: tail outputs (runs LAST; reclaims W2^T scratch in the tail region).
// ---------------------------------------------------------------------------
__launch_bounds__(256)
__global__ void tail_kernel(const float* __restrict__ pos_skip,
                            float* __restrict__ outp, int mode)
{
    const int i = blockIdx.x * 256 + threadIdx.x;
    if (i < POS_ELEMS) outp[i] = pos_skip[i];
    const int bi = i - POS_ELEMS;
    if (bi >= 0 && bi < M_ROWS) {
        if (mode == 0) {
            outp[POS_ELEMS + bi] = (float)(bi >> 12);
        } else {
            ((unsigned long long*)(outp + POS_ELEMS))[bi] = (unsigned long long)(bi >> 12);
        }
    }
}

// ---------------------------------------------------------------------------
extern "C" void kernel_launch(void* const* d_in, const int* in_sizes, int n_in,
                              void* d_out, int out_size, void* d_ws, size_t ws_size,
                              hipStream_t stream)
{
    const float* x        = (const float*)d_in[0];
    const float* pos      = (const float*)d_in[1];
    const float* x_skip   = (const float*)d_in[3];
    const float* pos_skip = (const float*)d_in[4];
    const float* w1  = (const float*)d_in[6];
    const float* b1  = (const float*)d_in[7];
    const float* g1  = (const float*)d_in[8];
    const float* be1 = (const float*)d_in[9];
    const float* m1  = (const float*)d_in[10];
    const float* v1  = (const float*)d_in[11];
    const float* w2  = (const float*)d_in[12];
    const float* b2  = (const float*)d_in[13];
    const float* g2  = (const float*)d_in[14];
    const float* be2 = (const float*)d_in[15];
    const float* m2  = (const float*)d_in[16];
    const float* v2  = (const float*)d_in[17];

    float* out = (float*)d_out;

    unsigned short* A1hi = (unsigned short*)d_out;
    unsigned short* A1lo = A1hi + (size_t)M_ROWS * K1;
    unsigned short* W1hi = A1lo + (size_t)M_ROWS * K1;
    unsigned short* W1lo = W1hi + (size_t)512 * K1;
    unsigned short* W2hi = (unsigned short*)(out + H_ELEMS);
    unsigned short* W2lo = W2hi + (size_t)512 * 512;
    unsigned short* h1hi = (unsigned short*)d_ws;
    unsigned short* h1lo = h1hi + H_ELEMS;

    // 1) producers
    knn_interp_kernel<<<NB * (NF / QB), 256, 0, stream>>>(x, pos, pos_skip, A1hi, A1lo);
    conv_skip_kernel<<<M_ROWS * 32 / 256, 256, 0, stream>>>(x_skip, A1hi, A1lo);
    conv_w_kernel<<<(K1 * 512 + 255) / 256, 256, 0, stream>>>(w1, W1hi, W1lo, K1);
    conv_w_kernel<<<(512 * 512 + 255) / 256, 256, 0, stream>>>(w2, W2hi, W2lo, 512);

    // 2) Layer 1: [65536 x 384] @ [384 x 512] -> split h1 planes
    gemm_bf3s<true><<<dim3(4 * (M_ROWS / 128)), 256, 0, stream>>>(
        A1hi, A1lo, W1hi, W1lo, K1, b1, g1, be1, m1, v1,
        nullptr, h1hi, h1lo);

    // 3) Layer 2: [65536 x 512] @ [512 x 512] -> f32 out
    gemm_bf3s<false><<<dim3(4 * (M_ROWS / 128)), 256, 0, stream>>>(
        h1hi, h1lo, W2hi, W2lo, HW_, b2, g2, be2, m2, v2,
        out, nullptr, nullptr);

    // 4) tail
    const long long tail = (long long)out_size - (long long)H_ELEMS;
    if (tail > 0) {
        const int mode = (tail - POS_ELEMS >= 2 * M_ROWS) ? 1 : 0;
        tail_kernel<<<(POS_ELEMS + M_ROWS + 255) / 256, 256, 0, stream>>>(
            pos_skip, out + H_ELEMS, mode);
    }
    (void)in_sizes; (void)n_in; (void)ws_size; (void)d_in;
}